// Round 10
// baseline (302.349 us; speedup 1.0000x reference)
//
#include <hip/hip_runtime.h>
#include <hip/hip_bf16.h>

// ---------------------------------------------------------------------------
// EncoderLayer (round 22): attn T5 setprio + XCD swizzle; WO/FF2 depth-6.
// r21 evidence: 256^2 2-phase at K=512 gains only ~11us (8 K-iters cannot
// amortize fill + vmcnt(0) drain at 1 blk/CU; full fix = 8-phase, deferred as
// sync-structure risk). This round, three independent catalog levers:
// (1) setprio(1) around attn QK^T/PV MFMA clusters (m191: +4-7% attn; r15
//     structure has wave role-split = the favorable regime, unlike r13).
// (2) attn XCD swizzle: 32 blocks share each (bh,z)'s 2MB K/V; bijective 1D
//     remap (id%8 = pair%8) puts them on ONE XCD's L2 (FETCH 69.8 vs ~50MB
//     logical = cross-XCD duplication today). Correctness-neutral.
// (3) WO/FF2 PIPE depth 3->6 (BK=32, 6 bufs, 108KB LDS, vmcnt(16) window =
//     5 iters ~700cy > HBM latency; peeled 12/8/4/0 tail).
// Attn core, gemm256, 128^2 PIPE=0, prep, combine, LN frozen.
// B=2, S=4096, D=512, H=8, DK=64, DFF=2048.
// ---------------------------------------------------------------------------

typedef unsigned short u16;
typedef unsigned int u32;
typedef __attribute__((ext_vector_type(2))) u32 u32x2;
typedef __attribute__((ext_vector_type(4))) u16 u16x4;
typedef __attribute__((ext_vector_type(8))) u16 u16x8;
typedef __attribute__((ext_vector_type(2))) float f32x2;
typedef __attribute__((ext_vector_type(4))) float f32x4;
typedef __attribute__((ext_vector_type(16))) float f32x16;
typedef __attribute__((ext_vector_type(8))) short bf16x8;

#define CB 2
#define CS 4096
#define CD 512
#define CH 8
#define CDK 64
#define CDFF 2048
#define NXC ((size_t)CB * CS * CD)
#define NSP 2
#define BH (CB * CH)
#define BHS (BH * CS)   // 65536

__device__ __forceinline__ float bf2f(u16 u) {
    union { u32 i; float f; } c;
    c.i = ((u32)u) << 16;
    return c.f;
}

__device__ __forceinline__ u16 f2bf(float f) {
    u32 x = __float_as_uint(f);
    u32 r = (x + 0x7fffu + ((x >> 16) & 1u)) >> 16;  // RNE
    return (u16)r;
}

__device__ __forceinline__ u32 packbf2(float a, float b) {
    __hip_bfloat162 h = __float22bfloat162_rn(float2{a, b});
    union { __hip_bfloat162 h; u32 u; } c;
    c.h = h;
    return c.u;
}

// HBM -> LDS DMA, 16 B/lane, dest = wave-uniform base + lane*16 (m97/m104).
__device__ __forceinline__ void dma16(const u16* g, u16* l) {
    __builtin_amdgcn_global_load_lds(
        (const __attribute__((address_space(1))) void*)g,
        (__attribute__((address_space(3))) void*)l, 16, 0, 0);
}

// ---------------------------------------------------------------------------
// Dtype detection (bf16-packed vs fp32). flag=1 -> bf16.
// ---------------------------------------------------------------------------
__global__ void detect_dtype(const u32* __restrict__ xw, int* __restrict__ flag) {
    __shared__ int red[256];
    int sane = 0;
    for (int i = threadIdx.x; i < 2048; i += 256) {
        u32 w = xw[i];
        u32 lo = w & 0xFFFFu;
        u32 e = (lo >> 7) & 0xFFu;
        if (lo == 0u || lo == 0x8000u || (e >= 96u && e <= 159u)) sane++;
    }
    red[threadIdx.x] = sane;
    __syncthreads();
    for (int s = 128; s > 0; s >>= 1) {
        if ((int)threadIdx.x < s) red[threadIdx.x] += red[threadIdx.x + s];
        __syncthreads();
    }
    if (threadIdx.x == 0) *flag = (red[0] >= 1843) ? 1 : 0;
}

__global__ __launch_bounds__(256) void convert_bf16(
    const void* __restrict__ src, u16* __restrict__ dst, int n,
    const int* __restrict__ flag)
{
    const bool isbf = (*flag != 0);
    const int n8 = n >> 3;
    int i = blockIdx.x * 256 + threadIdx.x;
    const int stride = gridDim.x * 256;
    if (isbf) {
        const u16x8* s = (const u16x8*)src;
        u16x8* d = (u16x8*)dst;
        for (; i < n8; i += stride) d[i] = s[i];
    } else {
        const f32x4* s = (const f32x4*)src;
        for (; i < n8; i += stride) {
            f32x4 a = s[2 * i];
            f32x4 b = s[2 * i + 1];
            u16x8 o;
#pragma unroll
            for (int e = 0; e < 4; e++) {
                o[e] = f2bf(a[e]);
                o[4 + e] = f2bf(b[e]);
            }
            *(u16x8*)&dst[(size_t)i * 8] = o;
        }
    }
    if (blockIdx.x == 0 && threadIdx.x == 0) {
        for (int r = n8 * 8; r < n; r++) {
            if (isbf) dst[r] = ((const u16*)src)[r];
            else dst[r] = f2bf(((const float*)src)[r]);
        }
    }
}

// ---------------------------------------------------------------------------
// Fused preprocessing: 6 weight transposes + mask bitmap + small converts in
// ONE dispatch. Block ranges from a descriptor (cum[] prefix sums).
// ---------------------------------------------------------------------------
struct PrepArgs {
    const void* tsrc[6];
    u16* tdst[6];
    int R[6], Cc[6], nbx[6];
    int cum[7];            // transpose block prefix; cum[6] = total transpose blocks
    const int* mask;
    unsigned long long* bits;
    const void* ssrc[6];
    u16* sdst[6];
    int sn[6];
};

__global__ __launch_bounds__(256) void prep_all(PrepArgs pa, const int* __restrict__ flag) {
    const int bid = blockIdx.x;
    const int tid = threadIdx.x;
    if (bid < pa.cum[6]) {
        // ---- weight transpose (32x32 LDS tiles)
        __shared__ float t[32][33];
        int w = 0;
#pragma unroll
        for (int k = 1; k < 6; k++) w += (bid >= pa.cum[k]) ? 1 : 0;
        const int local = bid - pa.cum[w];
        const int nbx = pa.nbx[w];
        const int bx = local % nbx;
        const int by = local / nbx;
        const int R = pa.R[w];
        const int Cc = pa.Cc[w];
        const void* src = pa.tsrc[w];
        u16* dst = pa.tdst[w];
        const bool isbf = (*flag != 0);
        const int r0 = by * 32;
        const int c0 = bx * 32;
        const int col = tid & 31;
        const int row = tid >> 5;
#pragma unroll
        for (int it = 0; it < 4; it++) {
            int rr = row + it * 8;
            float v;
            if (isbf) v = bf2f(((const u16*)src)[(size_t)(r0 + rr) * Cc + c0 + col]);
            else v = ((const float*)src)[(size_t)(r0 + rr) * Cc + c0 + col];
            t[rr][col] = v;
        }
        __syncthreads();
#pragma unroll
        for (int it = 0; it < 4; it++) {
            int rr = row + it * 8;
            dst[(size_t)(c0 + rr) * R + r0 + col] = f2bf(t[col][rr]);
        }
    } else if (bid < pa.cum[6] + 32) {
        // ---- mask bitmap: bits[b*64+t] = ballot over 64 keys of tile t
        const int local = bid - pa.cum[6];
        int w = local * 4 + (tid >> 6);
        int lane = tid & 63;
        int b = w >> 6, t = w & 63;
        int val = pa.mask[b * CS + t * 64 + lane];
        unsigned long long bal = __ballot(val != 0);
        if (lane == 0) pa.bits[w] = bal;
    } else {
        // ---- small converts
        const bool isbf = (*flag != 0);
        for (int t = 0; t < 6; t++) {
            for (int i = tid; i < pa.sn[t]; i += 256) {
                if (isbf) pa.sdst[t][i] = ((const u16*)pa.ssrc[t])[i];
                else pa.sdst[t][i] = f2bf(((const float*)pa.ssrc[t])[i]);
            }
        }
    }
}

#define F_SPLIT 1
#define F_BIAS  2
#define F_RELU  4

// ---------------------------------------------------------------------------
// gemm256 (r21, frozen): 256x256 tile, 512 thr (8 waves 2Mx4N), BK=64,
// double-buffered, minimum-2-phase, XOR-swizzled staging, LDS-transpose
// epilogue. QKV grid 192, FF1 grid 256.
// ---------------------------------------------------------------------------
template <int FLAGS>
__global__ __launch_bounds__(512, 2) void gemm256(
    const u16* __restrict__ A, const u16* __restrict__ Bt,
    const u16* __restrict__ bias, u16* __restrict__ C,
    int M, int N, int K)
{
    // [buf0: A 16384 | B 16384][buf1: A | B][8 x 1536 epilogue slices]
    __shared__ __align__(16) u16 POOL[65536 + 8 * 1536];

    const int tid = threadIdx.x;          // 0..511
    const int lane = tid & 63;
    const int wave = tid >> 6;            // 0..7
    const int lrow = lane & 15;
    const int quad = lane >> 4;
    const int rswg = lrow & 7;
    const int wm = wave >> 2;             // 0..1
    const int wn = wave & 3;              // 0..3
    const int m0 = blockIdx.y * 256;
    const int n0 = blockIdx.x * 256;

    const u16* Asrc[4];
    const u16* Bsrc[4];
#pragma unroll
    for (int r = 0; r < 4; r++) {
        const int idx = r * 512 + tid;
        const int row = idx >> 3;
        const int g = (idx & 7) ^ (row & 7);
        Asrc[r] = A + (size_t)(m0 + row) * K + g * 8;
        Bsrc[r] = Bt + (size_t)(n0 + row) * K + g * 8;
    }

#define STG256(BUF, K0)                                                      \
    {                                                                        \
        _Pragma("unroll")                                                    \
        for (int r = 0; r < 4; r++) {                                        \
            dma16(Asrc[r] + (K0), &POOL[(BUF) * 32768 + r * 4096 + wave * 512]); \
            dma16(Bsrc[r] + (K0), &POOL[(BUF) * 32768 + 16384 + r * 4096 + wave * 512]); \
        }                                                                    \
    }

    f32x4 acc[8][4];
#pragma unroll
    for (int mi = 0; mi < 8; mi++)
#pragma unroll
        for (int ni = 0; ni < 4; ni++) acc[mi][ni] = f32x4{0.f, 0.f, 0.f, 0.f};

    const int NT = K >> 6;
    STG256(0, 0)

    for (int j = 0; j < NT; j++) {
        asm volatile("s_waitcnt vmcnt(0)" ::: "memory");
        __builtin_amdgcn_sched_barrier(0);
        __builtin_amdgcn_s_barrier();
        __builtin_amdgcn_sched_barrier(0);
        if (j + 1 < NT) STG256((j + 1) & 1, (j + 1) * 64)

        const char* Ab = (const char*)&POOL[(j & 1) * 32768];
        const char* Bb = (const char*)&POOL[(j & 1) * 32768 + 16384];
#pragma unroll
        for (int ks = 0; ks < 2; ks++) {
            bf16x8 af[8], bfr[4];
#pragma unroll
            for (int mi = 0; mi < 8; mi++) {
                const int row = wm * 128 + mi * 16 + lrow;
                af[mi] = *(const bf16x8*)(Ab + row * 128 +
                                          (((ks * 4 + quad) ^ rswg) << 4));
            }
#pragma unroll
            for (int ni = 0; ni < 4; ni++) {
                const int row = wn * 64 + ni * 16 + lrow;
                bfr[ni] = *(const bf16x8*)(Bb + row * 128 +
                                           (((ks * 4 + quad) ^ rswg) << 4));
            }
#pragma unroll
            for (int mi = 0; mi < 8; mi++)
#pragma unroll
                for (int ni = 0; ni < 4; ni++)
                    acc[mi][ni] = __builtin_amdgcn_mfma_f32_16x16x32_bf16(
                        af[mi], bfr[ni], acc[mi][ni], 0, 0, 0);
        }
    }
#undef STG256

    // ---- epilogue: per-wave LDS-transpose store (3KB slice, wave-private).
    u16* st = POOL + 65536 + wave * 1536;
    const int mbase = m0 + wm * 128;
    const int nbase = n0 + wn * 64;
    const int msub = mbase & 4095;
    const int bb = mbase >> 12;
    const bool vpath = (FLAGS & F_SPLIT) && ((nbase >> 9) == 2);

    if (vpath) {
        const int h = (nbase >> 6) & 7;
        u16* vdst = C + 2 * NXC + (((size_t)(bb * CH + h)) * CDK) * CS;
#pragma unroll
        for (int mi = 0; mi < 8; mi++) {
#pragma unroll
            for (int ni = 0; ni < 4; ni++)
#pragma unroll
                for (int r = 0; r < 4; r++)
                    st[(ni * 16 + lrow) * 24 + quad * 4 + r] = f2bf(acc[mi][ni][r]);
#pragma unroll
            for (int rr = 0; rr < 2; rr++) {
                const int idx = rr * 64 + lane;
                const int dk = idx >> 1;
                const int sch = idx & 1;
                u16x8 val = *(const u16x8*)&st[dk * 24 + sch * 8];
                *(u16x8*)&vdst[(size_t)dk * CS + msub + mi * 16 + sch * 8] = val;
            }
        }
    } else {
        float bv[4];
        if (FLAGS & F_BIAS) {
#pragma unroll
            for (int ni = 0; ni < 4; ni++) bv[ni] = bf2f(bias[nbase + ni * 16 + lrow]);
        }
        const int proj = nbase >> 9;
        const int h = (nbase >> 6) & 7;
        u16* qkdst = C + (size_t)proj * NXC + (((size_t)(bb * CH + h)) * CS) * CDK;
#pragma unroll
        for (int mi = 0; mi < 8; mi++) {
#pragma unroll
            for (int ni = 0; ni < 4; ni++)
#pragma unroll
                for (int r = 0; r < 4; r++) {
                    float val = acc[mi][ni][r];
                    if (FLAGS & F_BIAS) val += bv[ni];
                    if (FLAGS & F_RELU) val = fmaxf(val, 0.f);
                    st[(quad * 4 + r) * 68 + ni * 16 + lrow] = f2bf(val);
                }
#pragma unroll
            for (int rr = 0; rr < 2; rr++) {
                const int idx = rr * 64 + lane;
                const int row = idx >> 3;
                const int ch = idx & 7;
                u16x4 lo = *(const u16x4*)&st[row * 68 + ch * 8];
                u16x4 hi = *(const u16x4*)&st[row * 68 + ch * 8 + 4];
                u16x8 val;
#pragma unroll
                for (int e = 0; e < 4; e++) { val[e] = lo[e]; val[4 + e] = hi[e]; }
                u16* p;
                if (FLAGS & F_SPLIT)
                    p = qkdst + (size_t)(msub + mi * 16 + row) * CDK + ch * 8;
                else
                    p = C + (size_t)(mbase + mi * 16 + row) * N + nbase + ch * 8;
                *(u16x8*)p = val;
            }
        }
    }
}

// ---------------------------------------------------------------------------
// MFMA GEMM 128^2. PIPE=1 (WO/FF2, 1-block/CU): r22 depth-6 rotating buffers
// (BK=32, 108KB LDS) -- stage window 5 iters ~700cy > HBM latency; peeled
// vmcnt 12/8/4/0 tail. PIPE=0 kept (unused this round).
// ---------------------------------------------------------------------------
template <int FLAGS, int PIPE>
__global__ __launch_bounds__(256, PIPE ? 1 : 3) void gemm_mfma(
    const u16* __restrict__ A, const u16* __restrict__ Bt,
    const u16* __restrict__ bias, u16* __restrict__ C,
    int M, int N, int K)
{
    constexpr int ABn = PIPE ? 24576 : 8192;   // u16 per matrix region
    __shared__ __align__(16) u16 POOL[2 * ABn + 4 * 1536];
    u16* ASb = POOL;
    u16* BSb = POOL + ABn;

    const int tid = threadIdx.x;
    const int lane = tid & 63;
    const int wave = tid >> 6;
    const int lrow = lane & 15;
    const int quad = lane >> 4;
    const int wm = wave & 1;
    const int wn = wave >> 1;
    const int m0 = blockIdx.y * 128;
    const int n0 = blockIdx.x * 128;

    f32x4 acc[4][4];
#pragma unroll
    for (int i = 0; i < 4; i++)
#pragma unroll
        for (int j = 0; j < 4; j++) acc[i][j] = f32x4{0.f, 0.f, 0.f, 0.f};

    if constexpr (PIPE) {
        // depth-6 counted-vmcnt pipeline, BK=32. Buffers rotate mod 6 (x4096
        // u16). Prologue stages 0..4; iter j waits stage j (vmcnt(16) in
        // steady state: outstanding = stages j..j+4 = 20 loads, retire 4),
        // stages j+5, computes buf j%6. Peeled tail 12/8/4/0.
        const int idx0 = wave * 128 + lane;
        const int idx1 = idx0 + 64;
        const u16* Ap0 = A + (size_t)(m0 + (idx0 >> 2)) * K + (idx0 & 3) * 8;
        const u16* Ap1 = A + (size_t)(m0 + (idx1 >> 2)) * K + (idx1 & 3) * 8;
        const u16* Bp0 = Bt + (size_t)(n0 + (idx0 >> 2)) * K + (idx0 & 3) * 8;
        const u16* Bp1 = Bt + (size_t)(n0 + (idx1 >> 2)) * K + (idx1 & 3) * 8;
        const int NK = K >> 5;   // >= 6 required (16 or 64 here)

#define PSTAGE(BOFF, KOFF)                                                   \
        {                                                                    \
            dma16(Ap0 + (KOFF), ASb + (BOFF) + wave * 1024);                 \
            dma16(Ap1 + (KOFF), ASb + (BOFF) + wave * 1024 + 512);           \
            dma16(Bp0 + (KOFF), BSb + (BOFF) + wave * 1024);                 \
            dma16(Bp1 + (KOFF), BSb + (BOFF) + wave * 1024 + 512);           \
        }
#define PITER(VMASM, DOS, JS)                                                \
        {                                                                    \
            asm volatile(VMASM ::: "memory");                                \
            __builtin_amdgcn_sched_barrier(0);                               \
            __builtin_amdgcn_s_barrier();                                    \
            __builtin_amdgcn_sched_barrier(0);                               \
            if (DOS) {                                                       \
                u32 bS = bR + 20480u;                                        \
                if (bS >= 24576u) bS -= 24576u;                              \
                PSTAGE(bS, ((JS) + 5) * 32)                                  \
            }                                                                \
            bf16x8 af[4], bfr[4];                                            \
            _Pragma("unroll")                                                \
            for (int i = 0; i < 4; i++)                                      \
                af[i] = *(const bf16x8*)&ASb[bR + (wm * 64 + i * 16 + lrow) * 32 + quad * 8]; \
            _Pragma("unroll")                                                \
            for (int jj = 0; jj < 4; jj++)                                   \
                bfr[jj] = *(const bf16x8*)&BSb[bR + (wn * 64 + jj * 16 + lrow) * 32 + quad * 8]; \
            _Pragma("unroll")                                                \
            for (int i = 0; i < 4; i++)                                      \
                _Pragma("unroll")                                            \
                for (int jj = 0; jj < 4; jj++)                               \
                    acc[i][jj] = __builtin_amdgcn_mfma_f32_16x16x32_bf16(    \
                        af[i], bfr[jj], acc[i][jj], 0, 0, 0);                \
            bR += 4096u;                                                     \
            if (bR == 24576u) bR = 0u;                                       \
        }

        PSTAGE(0, 0)
        PSTAGE(4096, 32)
        PSTAGE(8192, 64)
        PSTAGE(12288, 96)
        PSTAGE(16384, 128)
        u32 bR = 0;
        for (int js = 0; js < NK - 4; js++) {
            PITER("s_waitcnt vmcnt(16)", (js + 5 < NK), js)
        }
        PITER("s_waitcnt vmcnt(12)", 0, 0)
        PITER("s_waitcnt vmcnt(8)", 0, 0)
        PITER("s_waitcnt vmcnt(4)", 0, 0)
        PITER("s_waitcnt vmcnt(0)", 0, 0)
#undef PITER
#undef PSTAGE
    } else {
        const int rswg = lrow & 7;
        const u16* Aps[4];
        const u16* Bps[4];
        u16* Adst[4];
        u16* Bdst[4];
#pragma unroll
        for (int r = 0; r < 4; r++) {
            const int idx = r * 256 + tid;
            const int row = idx >> 3;
            const int g = (idx & 7) ^ (row & 7);
            Aps[r] = A + (size_t)(m0 + row) * K + g * 8;
            Bps[r] = Bt + (size_t)(n0 + row) * K + g * 8;
            Adst[r] = &ASb[r * 2048 + wave * 512];
            Bdst[r] = &BSb[r * 2048 + wave * 512];
        }
        const char* As8 = (const char*)ASb;
        const char* Bs8 = (const char*)BSb;

        for (int k0 = 0; k0 < K; k0 += 64) {
            __syncthreads();
#pragma unroll
            for (int r = 0; r < 4; r++) {
                dma16(Aps[r] + k0, Adst[r]);
                dma16(Bps[r] + k0, Bdst[r]);
            }
            __syncthreads();

#pragma unroll
            for (int kk = 0; kk < 2; kk++) {
                bf16x8 af[4], bfr[4];
#pragma unroll
                for (int i = 0; i < 4; i++) {
                    const int row = wm * 64 + i * 16 + lrow;
                    af[i] = *(const bf16x8*)(As8 + row * 128 +
                                             (((kk * 4 + quad) ^ rswg) << 4));
                }
#pragma unroll
                for (int j = 0; j < 4; j++) {
                    const int row = wn * 64 + j * 16 + lrow;
                    bfr[j] = *(const bf16x8*)(Bs8 + row * 128 +
                                              (((kk * 4 + quad) ^ rswg) << 4));
                }
#pragma unroll
                for (int i = 0; i < 4; i++)
#pragma unroll
                    for (int j = 0; j < 4; j++)
                        acc[i][j] = __builtin_amdgcn_mfma_f32_16x16x32_bf16(
                            af[i], bfr[j], acc[i][j], 0, 0, 0);
            }
        }
    }

    // ---- epilogue: per-wave LDS-transpose store (3KB slice, no barriers).
    u16* st = POOL + 2 * ABn + wave * 1536;
    const int mbase = m0 + wm * 64;
    const int nbase = n0 + wn * 64;
    const int msub = mbase & 4095;
    const int bb = mbase >> 12;
    const bool vpath = (FLAGS & F_SPLIT) && ((nbase >> 9) == 2);

    if (vpath) {
        const int h = (nbase >> 6) & 7;
        u16* vdst = C + 2 * NXC + (((size_t)(bb * CH + h)) * CDK) * CS;
#pragma unroll
        for (int i = 0; i < 4; i++) {
#pragma unroll
            for (int j = 0; j < 4; j++)
#pragma unroll
                for (int r = 0; r < 4; r++)
                    st[(j * 16 + lrow) * 24 + quad * 4 + r] = f2bf(acc[i][j][r]);
#pragma unroll
            for (int rr = 0; rr < 2; rr++) {
                const int idx = rr * 64 + lane;
                const int dk = idx >> 1;
                const int sch = idx & 1;
                u16x8 val = *(const u16x8*)&st[dk * 24 + sch * 8];
                *(u16x8*)&vdst[(size_t)dk * CS + msub + i * 16 + sch * 8] = val;
            }
        }
    } else {
        float bv[4];
        if (FLAGS & F_BIAS) {
#pragma unroll
            for (int j = 0; j < 4; j++) bv[j] = bf2f(bias[nbase + j * 16 + lrow]);
        }
        const int proj = nbase >> 9;
        const int h = (nbase >> 6) & 7;
        u16* qkdst = C + (size_t)proj * NXC + (((size_t)(bb * CH + h)) * CS) * CDK;
#pragma unroll
        for (int i = 0; i < 4; i++) {
#pragma unroll
            for (int j = 0; j < 4; j++)
#pragma unroll
                for (int r = 0; r < 4; r++) {
                    float val = acc[i][j][r];
                    if (FLAGS & F_BIAS) val += bv[j];
                    if (FLAGS & F_RELU) val = fmaxf(val, 0.f);
                    st[(quad * 4 + r) * 68 + j * 16 + lrow] = f2bf(val);
                }
#pragma unroll
            for (int rr = 0; rr < 2; rr++) {
                const int idx = rr * 64 + lane;
                const int row = idx >> 3;
                const int ch = idx & 7;
                u16x4 lo = *(const u16x4*)&st[row * 68 + ch * 8];
                u16x4 hi = *(const u16x4*)&st[row * 68 + ch * 8 + 4];
                u16x8 val;
#pragma unroll
                for (int e = 0; e < 4; e++) { val[e] = lo[e]; val[4 + e] = hi[e]; }
                u16* p;
                if (FLAGS & F_SPLIT)
                    p = qkdst + (size_t)(msub + i * 16 + row) * CDK + ch * 8;
                else
                    p = C + (size_t)(mbase + i * 16 + row) * N + nbase + ch * 8;
                *(u16x8*)p = val;
            }
        }
    }
}

// ---------------------------------------------------------------------------
// Split-K transposed-score MFMA flash attention (r15 structure + r22 T5
// setprio + XCD swizzle). 1D grid of 1024; bijective remap puts the 32
// blocks sharing each (bh,z)'s K/V on one XCD (id%8 = pair%8 under
// round-robin). Fast path: depth-3 K / depth-2 V counted-vmcnt (4/6).
// Epilogue stores transposed pOT[z][bh][dk][s].
// ---------------------------------------------------------------------------
__global__ __launch_bounds__(256, 4) void mfma_attn2(
    const u16* __restrict__ Qb, const u16* __restrict__ Kb,
    const u16* __restrict__ Vt, const unsigned long long* __restrict__ bits,
    u16* __restrict__ pOT, float* __restrict__ Ls)
{
    __shared__ u16 KB[3][4096];   // K tiles, rotating depth-3
    __shared__ u16 VB[2][4096];   // V tiles, parity depth-2

    const int tid = threadIdx.x;
    const int lane = tid & 63;
    const int wave = tid >> 6;
    const int qcol = lane & 31;
    const int hf = lane >> 5;

    // XCD swizzle: id -> (pair p = bh*2+z, qtile qx) with id%8 == p%8.
    const int id = blockIdx.x;
    const int xcd = id & 7;
    const int jL = id >> 3;
    const int p = ((jL >> 5) << 3) | xcd;
    const int qx = jL & 31;
    const int bh = p >> 1;
    const int z = p & 1;
    const int b = bh >> 3;
    const int q0 = qx * 128 + wave * 32;

    const float SC = 0.125f * 1.44269504088896340736f;  // 1/sqrt(64)*log2(e)

    bf16x8 bq[4];
    const u16* qp = Qb + ((size_t)bh * CS + q0 + qcol) * CDK + hf * 8;
#pragma unroll
    for (int c = 0; c < 4; c++) {
        bf16x8 raw = *(const bf16x8*)(qp + c * 16);
        union { u32 u[4]; bf16x8 v; } cv;
#pragma unroll
        for (int j = 0; j < 4; j++)
            cv.u[j] = packbf2(bf2f((u16)raw[2 * j]) * SC, bf2f((u16)raw[2 * j + 1]) * SC);
        bq[c] = cv.v;
    }

    // Opaque zero accumulator (16 VGPRs, no remat) for first QK^T MFMA.
    f32x4 z4 = {0.f, 0.f, 0.f, 0.f};
    asm volatile("" : "+v"(z4));
    f32x16 zero16;
#pragma unroll
    for (int i = 0; i < 16; i++) zero16[i] = z4[i & 3];

    f32x16 ot[2];
#pragma unroll
    for (int dt = 0; dt < 2; dt++)
#pragma unroll
        for (int i = 0; i < 16; i++) ot[dt][i] = 0.f;
    float lh = 0.f;   // per-half row-sum; cross-half reduce in epilogue

    const u16* kbase = Kb + (size_t)bh * CS * CDK;
    const u16* vbase = Vt + (size_t)bh * CDK * CS;
    const unsigned long long* bp = bits + b * 64;

    const int t0 = z * (CS / NSP);
    const int t1 = t0 + (CS / NSP);

    // Loop-invariant per-lane LDS byte offsets for the swizzled K/V reads.
    const int rsw = qcol & 7;
    int koff[2][4];
#pragma unroll
    for (int rt = 0; rt < 2; rt++)
#pragma unroll
        for (int c = 0; c < 4; c++)
            koff[rt][c] = ((rt * 32 + qcol) * 64 + (((2 * c + hf) ^ rsw) * 8)) * 2;
    const char* kb0 = (const char*)&KB[0][0];
    const char* vb0 = (const char*)&VB[0][0];

    const int w2 = wave * 2;

#define STAGE_K(KOFFB, t)                                                    \
    {                                                                        \
        const u16* kb_ = kbase + (size_t)(t) * CDK;                          \
        _Pragma("unroll")                                                    \
        for (int n = 0; n < 2; n++) {                                        \
            int idx = (w2 + n) * 64 + lane;                                  \
            int row = idx >> 3;                                              \
            int g = (idx & 7) ^ (row & 7);                                   \
            dma16(kb_ + row * CDK + g * 8,                                   \
                  (u16*)((char*)&KB[0][0] + (KOFFB) + (w2 + n) * 1024));     \
        }                                                                    \
    }
#define STAGE_V(P, t)                                                        \
    {                                                                        \
        const u16* vb_ = vbase + (t);                                        \
        _Pragma("unroll")                                                    \
        for (int n = 0; n < 2; n++) {                                        \
            int idx = (w2 + n) * 64 + lane;                                  \
            int row = idx >> 3;                                              \
            int g = (idx & 7) ^ (row & 7);                                   \
            dma16(vb_ + (size_t)row * CS + g * 8,                            \
                  (u16*)((char*)&VB[0][0] + (P) * 8192 + (w2 + n) * 1024));  \
        }                                                                    \
    }

// Tile compute body. MIDSYNC inserted after the mt=0 softmax (before any
// V read). MASKED is a compile-time flag; BM only evaluated when MASKED.
// T5: setprio(1) around the QK^T and PV MFMA clusters (m191: +4-7% attn).
#define TBODY(KROFF, VOFF, BM, MASKED, MIDSYNC)                              \
    {                                                                        \
        f32x2 racc = {0.f, 0.f};                                             \
        _Pragma("unroll")                                                    \
        for (int mt = 0; mt < 2; mt++) {                                     \
            f32x16 s;                                                        \
            __builtin_amdgcn_s_setprio(1);                                   \
            _Pragma("unroll")                                                \
            for (int c = 0; c < 4; c++) {                                    \
                bf16x8 ak = *(const bf16x8*)(kb0 + (KROFF) + koff[mt][c]);   \
                s = __builtin_amdgcn_mfma_f32_32x32x16_bf16(                 \
                    ak, bq[c], (c == 0) ? zero16 : s, 0, 0, 0);              \
            }                                                                \
            __builtin_amdgcn_s_setprio(0);                                   \
            if (MASKED) {                                                    \
                const unsigned long long bm_ = (BM);                         \
                if (bm_ != ~0ull) {                                          \
                    _Pragma("unroll")                                        \
                    for (int i = 0; i < 16; i++) {                           \
                        const int key = (i & 3) + 8 * (i >> 2) + 4 * hf + 32 * mt; \
                        if (!((bm_ >> key) & 1ull)) s[i] = -1e30f;           \
                    }                                                        \
                }                                                            \
            }                                                                \
            u32 pk[8];                                                       \
            _Pragma("unroll")                                                \
            for (int g = 0; g < 4; g++) {                                    \
                float p0 = __builtin_amdgcn_exp2f(s[4 * g + 0]);             \
                float p1 = __builtin_amdgcn_exp2f(s[4 * g + 1]);             \
                float p2 = __builtin_amdgcn_exp2f(s[4 * g + 2]);             \
                float p3 = __builtin_amdgcn_exp2f(s[4 * g + 3]);             \
                racc += f32x2{p0, p1};                                       \
                racc += f32x2{p2, p3};                                       \
                pk[2 * g + 0] = packbf2(p0, p1);                             \
                pk[2 * g + 1] = packbf2(p2, p3);                             \
            }                                                                \
            if (mt == 0) { MIDSYNC }                                         \
            _Pragma("unroll")                                                \
            for (int cc = 0; cc < 2; cc++) {                                 \
                u32x2 r0 = __builtin_amdgcn_permlane32_swap(                 \
                    pk[4 * cc + 0], pk[4 * cc + 2], false, false);           \
                u32x2 r1 = __builtin_amdgcn_permlane32_swap(                 \
                    pk[4 * cc + 1], pk[4 * cc + 3], false, false);           \
                union { u32 u[4]; bf16x8 v; } pf;                            \
                pf.u[0] = r0.x;                                              \
                pf.u[1] = r1.x;                                              \
                pf.u[2] = r0.y;                                              \
                pf.u[3] = r1.y;                                              \
                const int c = 2 * mt + cc;                                   \
                __builtin_amdgcn_s_setprio(1);                               \
                _Pragma("unroll")                                            \
                for (int dt = 0; dt < 2; dt++) {                             \
                    bf16x8 av = *(const bf16x8*)(vb0 + (VOFF) + koff[dt][c]); \
                    ot[dt] = __builtin_amdgcn_mfma_f32_32x32x16_bf16(        \
                        av, pf.v, ot[dt], 0, 0, 0);                          \
                }                                                            \
                __builtin_amdgcn_s_setprio(0);                               \
            }                                                                \
        }                                                                    \
        lh += racc.x + racc.y;                                               \
    }

// Pipelined fast-path tile. TOPASM ensures K(j) done, MIDASM ensures V(j)
// done; barriers make it cross-wave. Stages issued after the top barrier:
// V(j+1) first, then K(j+2) (issue order defines vmcnt retirement order).
#define FTILE(P, TT, KR, KS, DOV, DOK, TOPASM, MIDASM)                       \
    {                                                                        \
        asm volatile(TOPASM ::: "memory");                                   \
        __builtin_amdgcn_sched_barrier(0);                                   \
        __builtin_amdgcn_s_barrier();                                        \
        __builtin_amdgcn_sched_barrier(0);                                   \
        if (DOV) STAGE_V((P) ^ 1, (TT) + 64);                                \
        if (DOK) STAGE_K((KS), (TT) + 128);                                  \
        TBODY((KR), (P) * 8192, 0ull, 0,                                     \
              asm volatile(MIDASM ::: "memory");                             \
              __builtin_amdgcn_sched_barrier(0);                             \
              __builtin_amdgcn_s_barrier();                                  \
              __builtin_amdgcn_sched_barrier(0);)                            \
    }

    // ---- mask precheck (hoisted; no vector loads inside the counted loop)
    unsigned long long am = ~0ull;
    const int tb0 = t0 >> 6;
    for (int i = 0; i < 32; i++) am &= bp[tb0 + i];
    const bool allones = (am == ~0ull);

    if (allones) {
        // prologue: K(0), V(0), K(1)  (oldest-first order matters for vmcnt)
        STAGE_K(0, t0);
        STAGE_V(0, t0);
        STAGE_K(8192, t0 + 64);

        u32 kr = 0;
        for (int m = 0; m < 15; m++) {
            const int t = t0 + m * 128;
            const u32 kr1 = (kr == 16384u) ? 0u : kr + 8192u;
            const u32 ks0 = (kr1 == 16384u) ? 0u : kr1 + 8192u;
            FTILE(0, t, kr, ks0, 1, 1,
                  "s_waitcnt vmcnt(4)", "s_waitcnt vmcnt(6)")
            FTILE(1, t + 64, kr1, kr, 1, 1,
                  "s_waitcnt vmcnt(4)", "s_waitcnt vmcnt(6)")
            kr = ks0;
        }
        {   // tiles 30, 31 (peeled: adjusted counts, no K stages)
            const int t = t0 + 30 * 64;
            const u32 kr1 = (kr == 16384u) ? 0u : kr + 8192u;
            FTILE(0, t, kr, 0, 1, 0,
                  "s_waitcnt vmcnt(4)", "s_waitcnt vmcnt(4)")
            FTILE(1, t + 64, kr1, 0, 0, 0,
                  "s_waitcnt vmcnt(2)", "s_waitcnt vmcnt(0)")
        }
    } else {
        // slow path: depth-1 double buffer with __syncthreads.
        STAGE_K(0, t0);
        STAGE_V(0, t0);
        __syncthreads();
        for (int t = t0; t < t1; t += 64) {
            const int pp = (t >> 6) & 1;
            const u32 kro = (u32)pp * 8192u;
            if (t + 64 < t1) {
                STAGE_V(pp ^ 1, t + 64);
                STAGE_K((pp ^ 1) * 8192, t + 64);
            }
            TBODY(kro, pp * 8192, bp[t >> 6], 1, ;)
            __syncthreads();
        }
    }
#undef FTILE
#undef TBODY
#undef STAGE_V
#undef STAGE_K

    // ---- epilogue: cross-half l reduce, unnormalized partial O^T + l
    u32x2 rr = __builtin_amdgcn_permlane32_swap(
        __float_as_uint(lh), __float_as_uint(lh), false, false);
    const float l = lh + __uint_as_float(hf ? rr.x : rr.y);

    const int q_lin = bh * CS + q0 + qcol;
    if (hf == 0) Ls[z * BHS + q_lin] = l;
    const size_t pbase = ((size_t)(z * BH + bh) * CDK) * CS + q0 + qcol;
#pragma unroll
    for (int dt = 0; dt < 2; dt++)
#pragma unroll
        for (int i = 0; i < 16; i++) {
            const int dk = (i & 3) + 8 * (i >> 2) + 4 * hf + 32 * dt;
            pOT[pbase + (size_t)dk * CS] = f2bf(ot[dt][i]);
        }
}

// ---------------------------------------------------------------------------
// Combine NSP partials -> ctx [B,S,D]. Reads pOT coalesced along s, LDS
// transpose, writes ctx coalesced along d. grid (CS/64, BH).
// ---------------------------------------------------------------------------
__global__ __launch_bounds__(256) void attn_combine(
    const u16* __restrict__ pOT, const float* __restrict__ Ls,
    u16* __restrict__ ctx)
{
    __shared__ float linv[64];
    __shared__ u16 T[64][72];   // [s][dk], padded

    const int bh = blockIdx.y;
    const int s0 = blockIdx.x * 64;
    const int b = bh >> 3, h = bh & 7;
    const int tid = threadIdx.x;

    if (tid < 64) {
        float L = 0.f;
#pragma unroll
        for (int z = 0; z < NSP; z++) L += Ls[z * BHS + bh * CS + s0 + tid];
        linv[tid] = (L > 0.f) ? 1.f / L : 0.f;
    }
    __syncthreads();

    const int dk = tid >> 2;
    const int sc = (tid & 3) * 16;
    float acc[16] = {};
#pragma unroll
    for (int z = 0; z < NSP; z++) {
        const u16* p = pOT + ((size_t)(z * BH + bh) * CDK + dk) * CS + s0 + sc;
        u16x8 v0 = *(const u16x8*)p;
        u16x8 v1 = *(const u16x8*)(p + 8);
#pragma unroll
        for (int e = 0; e < 8; e++) {
            acc[e] += bf2f(v0[e]);
            acc[8 + e] += bf2f(v1[e]);
        }
    }
#pragma unroll
    for (int e = 0; e < 16; e++)
        T[sc + e][dk] = f2bf(acc[e] * linv[sc + e]);
    __syncthreads();

    const int sr = tid >> 2;
    const int dc = (tid & 3) * 16;
    u16x8 o0, o1;
#pragma unroll
    for (int e = 0; e < 8; e++) {
        o0[e] = T[sr][dc + e];
        o1[e] = T[sr][dc + 8 + e];
    }
    u16* cp = &ctx[((size_t)b * CS + s0 + sr) * CD + h * CDK + dc];
    *(u16x8*)cp = o0;
    *(u16x8*)(cp + 8) = o1;
}

// ---------------------------------------------------------------------------
// Residual + LayerNorm (unchanged).
// ---------------------------------------------------------------------------
__global__ __launch_bounds__(256) void ln_kernel(
    const u16* __restrict__ xa, const u16* __restrict__ xb,
    const u16* __restrict__ g, const u16* __restrict__ be,
    u16* __restrict__ outb, float* __restrict__ outf,
    const int* __restrict__ flag)
{
    const int lane = threadIdx.x & 63;
    const int wave = threadIdx.x >> 6;
    const size_t row = (size_t)blockIdx.x * 4 + wave;
    const int c0 = lane * 8;

    u16x8 av = *(const u16x8*)(xa + row * CD + c0);
    u16x8 bv = *(const u16x8*)(xb + row * CD + c0);

    float v[8];
    float s1 = 0.f, s2 = 0.f;
#pragma unroll
    for (int e = 0; e < 8; e++) {
        v[e] = bf2f(av[e]) + bf2f(bv[e]);
        s1 += v[e];
        s2 += v[e] * v[e];
    }
#pragma unroll
    for (int off = 32; off > 0; off >>= 1) {
        s1 += __shfl_xor(s1, off, 64);
        s2 += __shfl_xor(s2, off, 64);
    }
    const float mu = s1 * (1.f / CD);
    const float var = fmaxf(s2 * (1.f / CD) - mu * mu, 0.f);
    const float r = rsqrtf(var + 1e-5f);

    u16x8 gv = *(const u16x8*)(g + c0);
    u16x8 ev = *(const u16x8*)(be + c0);
    float res[8];
#pragma unroll
    for (int e = 0; e < 8; e++)
        res[e] = (v[e] - mu) * r * bf2f(gv[e]) + bf2f(ev[e]);

    const int flg = *flag;
    const bool f32out = (outf != nullptr) && (flg == 0);
    if (f32out) {
        float4 o0 = make_float4(res[0], res[1], res[2], res[3]);
        float4 o1 = make_float4(res[4], res[5], res[6], res[7]);
        *(float4*)(outf + row * CD + c0) = o0;
        *(float4*)(outf + row * CD + c0 + 4) = o1;
    } else {
        u16x8 ov;
#pragma unroll
        for (int e = 0; e < 8; e++) ov[e] = f2bf(res[e]);
        *(u16x8*)(outb + row * CD + c0) = ov;
    }
}

// ---------------------------------------------------------------------------

extern "C" void kernel_launch(void* const* d_in, const int* in_sizes, int n_in,
                              void* d_out, int out_size, void* d_ws, size_t ws_size,
                              hipStream_t stream)
{
    const void* x_raw   = d_in[0];
    const int*  mask    = (const int*)d_in[1];
    const void* wq_raw  = d_in[2];
    const void* wk_raw  = d_in[3];
    const void* wv_raw  = d_in[4];
    const void* wo_raw  = d_in[5];
    const void* w1_raw  = d_in[6];
    const void* b1_raw  = d_in[7];
    const void* w2_raw  = d_in[8];
    const void* b2_raw  = d_in[9];
    const void* g1_raw  = d_in[10];
    const void* be1_raw = d_in[11];
    const void* g2_raw  = d_in[12];
    const void* be2_raw = d_in[13];

    const size_t NX = NXC;
    const size_t WSZ = (size_t)CD * CD;
    const size_t W1SZ = (size_t)CD * CDFF;

    u16* ws = (u16*)d_ws;
    int* flag = (int*)d_ws;
    unsigned long long* bits = (unsigned long long*)(ws + 512);
    u16* base = ws + 1024;
    u16* xc  = base;
    u16* q   = base + 1 * NX;
    u16* k   = base + 2 * NX;
    u16* v   = base + 3 * NX;   // V^T [B,H,DK,S]
    u16* ctx = base + 4 * NX;
    u16* att = base + 5 * NX;   // also holds attn stats (Ls) pre-wo-gemm
    u16* x1  = base + 6 * NX;
    u16* ffo = base + 7 * NX;
    u16* ffh = base + 8 * NX;   // 4*NX; also holds attn partial O pre-FFN
    u16* wt  = base + 12 * NX;
    u16* wqkvT = wt;
    u16* woT = wqkvT + 3 * WSZ;
    u16* w1T = woT + WSZ;
    u16* w2T = w1T + W1SZ;
    u16* b1c = w2T + W1SZ;
    u16* b2c = b1c + CDFF;
    u16* g1c = b2c + CD;
    u16* be1c = g1c + CD;
    u16* g2c = be1c + CD;
    u16* be2c = g2c + CD;
    u16* wend = be2c + CD;

    const size_t need = (size_t)(wend - ws) * sizeof(u16);
    if (ws_size < need) return;
    (void)k;

    u16* pOT = ffh;                      // NSP*NX u16, [z][bh][dk][s]
    float* Ls = (float*)att;             // NSP*BHS floats

    detect_dtype<<<1, 256, 0, stream>>>((const u32*)x_raw, flag);

    convert_bf16<<<1024, 256, 0, stream>>>(x_raw, xc, (int)NX, flag);

    // ---- fused preprocessing: 6 transposes + mask bits + small converts
    PrepArgs pa;
    pa.tsrc[0] = wq_raw; pa.tdst[0] = wqkvT;           pa.R[0] = CD;   pa.Cc[0] = CD;
    pa.tsrc[1] = wk_raw; pa.tdst[1] = wqkvT + WSZ;     pa.R[1] = CD;   pa.Cc[1] = CD;
    pa.tsrc[2] = wv_raw; pa.tdst[2] = wqkvT + 2 * WSZ; pa.R[2] = CD;   pa.Cc[2] = CD;
    pa.tsrc[3] = wo_raw; pa.tdst[3] = woT;             pa.R[3] = CD;   pa.Cc[3] = CD;
    pa.tsrc[4] = w1_raw; pa.tdst[4] = w1T;             pa.R[4] = CD;   pa.Cc[4] = CDFF;
    pa.tsrc[5] = w2_raw; pa.tdst[5] = w2T;             pa.R[5] = CDFF; pa.Cc[5] = CD;
    int cum = 0;
    for (int w = 0; w < 6; w++) {
        pa.nbx[w] = pa.Cc[w] / 32;
        pa.cum[w] = cum;
        cum += (pa.Cc[w] / 32) * (pa.R[w] / 32);
    }
    pa.cum[6] = cum;                      // 3072
    pa.mask = mask;
    pa.bits = bits;
    pa.ssrc[0] = b1_raw;  pa.sdst[0] = b1c;  pa.sn[0] = CDFF;
    pa.ssrc[1] = b2_raw;  pa.sdst[1] = b2c;  pa.sn[1] = CD;
    pa.ssrc[2] = g1_raw;  pa.sdst[2] = g1c;  pa.sn[2] = CD;
    pa.ssrc[3] = be1_raw; pa.sdst[3] = be1c; pa.sn[3] = CD;
    pa.ssrc[4] = g2_raw;  pa.sdst[4] = g2c;  pa.sn[4] = CD;
    pa.ssrc[5] = be2_raw; pa.sdst[5] = be2c; pa.sn[5] = CD;
    prep_all<<<cum + 32 + 1, 256, 0, stream>>>(pa, flag);

    const int M = CB * CS;  // 8192

    // QKV + FF1 on the 256^2 8-wave kernel; WO + FF2 on the 128^2 PIPE=1.
    gemm256<F_SPLIT><<<dim3(1536 / 256, M / 256), 512, 0, stream>>>(
        xc, wqkvT, nullptr, q, M, 1536, CD);

    mfma_attn2<<<dim3(1024), 256, 0, stream>>>(q, k, v, bits, pOT, Ls);
    attn_combine<<<dim3(CS / 64, BH), 256, 0, stream>>>(pOT, Ls, ctx);

    gemm_mfma<0, 1><<<dim3(CD / 128, M / 128), 256, 0, stream>>>(
        ctx, woT, nullptr, att, M, CD, CD);

    ln_kernel<<<dim3(M / 4), 256, 0, stream>>>(xc, att, g1c, be1c, x1, nullptr, flag);

    gemm256<F_BIAS | F_RELU><<<dim3(CDFF / 256, M / 256), 512, 0, stream>>>(
        x1, w1T, b1c, ffh, M, CDFF, CD);
    gemm_mfma<F_BIAS, 1><<<dim3(CD / 128, M / 128), 256, 0, stream>>>(
        ffh, w2T, b2c, ffo, M, CD, CDFF);

    ln_kernel<<<dim3(M / 4), 256, 0, stream>>>(x1, ffo, g2c, be2c,
                                               (u16*)d_out, (float*)d_out, flag);
}

// Round 12
// 287.280 us; speedup vs baseline: 1.0525x; 1.0525x over previous
//
#include <hip/hip_runtime.h>
#include <hip/hip_bf16.h>

// ---------------------------------------------------------------------------
// EncoderLayer (round 23b, resubmit: r23 bench was an infra failure).
// r22 evidence: attn XCD swizzle cut FETCH 69.8->16.5MB (mechanism proven)
// but attn was latency-hidden (-3us only); WO/FF2 depth-6 regressed +4.4.
// Now: (1) detect_dtype + convert_bf16 folded into prep_all (per-block
// self-detect from x's first 8KB, block0 writes flag; 11->9 dispatches,
// no serial 1-block bubble); (2) WO/FF2 reverted to r20 depth-3 PIPE;
// (3) gemm256 gets the proven XCD remap (1D grid, same-A-panel blocks
// co-located per XCD L2). Attn (r22: setprio+swizzle), gemm256 core,
// combine, LN frozen. B=2,S=4096,D=512,H=8,DK=64,DFF=2048.
// ---------------------------------------------------------------------------

typedef unsigned short u16;
typedef unsigned int u32;
typedef __attribute__((ext_vector_type(2))) u32 u32x2;
typedef __attribute__((ext_vector_type(4))) u16 u16x4;
typedef __attribute__((ext_vector_type(8))) u16 u16x8;
typedef __attribute__((ext_vector_type(2))) float f32x2;
typedef __attribute__((ext_vector_type(4))) float f32x4;
typedef __attribute__((ext_vector_type(16))) float f32x16;
typedef __attribute__((ext_vector_type(8))) short bf16x8;

#define CB 2
#define CS 4096
#define CD 512
#define CH 8
#define CDK 64
#define CDFF 2048
#define NXC ((size_t)CB * CS * CD)
#define NSP 2
#define BH (CB * CH)
#define BHS (BH * CS)   // 65536

__device__ __forceinline__ float bf2f(u16 u) {
    union { u32 i; float f; } c;
    c.i = ((u32)u) << 16;
    return c.f;
}

__device__ __forceinline__ u16 f2bf(float f) {
    u32 x = __float_as_uint(f);
    u32 r = (x + 0x7fffu + ((x >> 16) & 1u)) >> 16;  // RNE
    return (u16)r;
}

__device__ __forceinline__ u32 packbf2(float a, float b) {
    __hip_bfloat162 h = __float22bfloat162_rn(float2{a, b});
    union { __hip_bfloat162 h; u32 u; } c;
    c.h = h;
    return c.u;
}

// HBM -> LDS DMA, 16 B/lane, dest = wave-uniform base + lane*16 (m97/m104).
__device__ __forceinline__ void dma16(const u16* g, u16* l) {
    __builtin_amdgcn_global_load_lds(
        (const __attribute__((address_space(1))) void*)g,
        (__attribute__((address_space(3))) void*)l, 16, 0, 0);
}

// ---------------------------------------------------------------------------
// Fused preprocessing (r23): per-block dtype self-detect + 6 weight
// transposes + mask bitmap + small converts + x conversion, ONE dispatch.
// Block ranges: [0,cum6) transpose | [cum6,cum6+32) mask | cum6+32 small |
// [cum6+33, cum6+33+1024) x-conversion. Block 0 also writes *flag (read by
// ln_kernel several dispatches later).
// ---------------------------------------------------------------------------
struct PrepArgs {
    const void* tsrc[6];
    u16* tdst[6];
    int R[6], Cc[6], nbx[6];
    int cum[7];            // transpose block prefix; cum[6] = total transpose blocks
    const int* mask;
    unsigned long long* bits;
    const void* ssrc[6];
    u16* sdst[6];
    int sn[6];
    const u32* xw;         // x as u32 words (for dtype detect)
    const void* xsrc;      // x raw
    u16* xdst;             // x as bf16
    int xn8;               // NX/8
};

__global__ __launch_bounds__(256) void prep_all(PrepArgs pa, int* __restrict__ flag) {
    __shared__ int red[256];
    __shared__ float t[32][33];
    const int bid = blockIdx.x;
    const int tid = threadIdx.x;

    // ---- self-detect dtype from first 8KB of x (identical across blocks)
    int sane = 0;
    for (int i = tid; i < 2048; i += 256) {
        u32 w = pa.xw[i];
        u32 lo = w & 0xFFFFu;
        u32 e = (lo >> 7) & 0xFFu;
        if (lo == 0u || lo == 0x8000u || (e >= 96u && e <= 159u)) sane++;
    }
    red[tid] = sane;
    __syncthreads();
    for (int s = 128; s > 0; s >>= 1) {
        if (tid < s) red[tid] += red[tid + s];
        __syncthreads();
    }
    const bool isbf = (red[0] >= 1843);
    if (bid == 0 && tid == 0) *flag = isbf ? 1 : 0;

    if (bid < pa.cum[6]) {
        // ---- weight transpose (32x32 LDS tiles)
        int w = 0;
#pragma unroll
        for (int k = 1; k < 6; k++) w += (bid >= pa.cum[k]) ? 1 : 0;
        const int local = bid - pa.cum[w];
        const int nbx = pa.nbx[w];
        const int bx = local % nbx;
        const int by = local / nbx;
        const int R = pa.R[w];
        const int Cc = pa.Cc[w];
        const void* src = pa.tsrc[w];
        u16* dst = pa.tdst[w];
        const int r0 = by * 32;
        const int c0 = bx * 32;
        const int col = tid & 31;
        const int row = tid >> 5;
#pragma unroll
        for (int it = 0; it < 4; it++) {
            int rr = row + it * 8;
            float v;
            if (isbf) v = bf2f(((const u16*)src)[(size_t)(r0 + rr) * Cc + c0 + col]);
            else v = ((const float*)src)[(size_t)(r0 + rr) * Cc + c0 + col];
            t[rr][col] = v;
        }
        __syncthreads();
#pragma unroll
        for (int it = 0; it < 4; it++) {
            int rr = row + it * 8;
            dst[(size_t)(c0 + rr) * R + r0 + col] = f2bf(t[col][rr]);
        }
    } else if (bid < pa.cum[6] + 32) {
        // ---- mask bitmap: bits[b*64+t] = ballot over 64 keys of tile t
        const int local = bid - pa.cum[6];
        int w = local * 4 + (tid >> 6);
        int lane = tid & 63;
        int b = w >> 6, tt = w & 63;
        int val = pa.mask[b * CS + tt * 64 + lane];
        unsigned long long bal = __ballot(val != 0);
        if (lane == 0) pa.bits[w] = bal;
    } else if (bid == pa.cum[6] + 32) {
        // ---- small converts
        for (int tc = 0; tc < 6; tc++) {
            for (int i = tid; i < pa.sn[tc]; i += 256) {
                if (isbf) pa.sdst[tc][i] = ((const u16*)pa.ssrc[tc])[i];
                else pa.sdst[tc][i] = f2bf(((const float*)pa.ssrc[tc])[i]);
            }
        }
    } else {
        // ---- x conversion (1024 blocks, grid-stride over xn8 u16x8 groups)
        const int local = bid - (pa.cum[6] + 33);
        int i = local * 256 + tid;
        const int stride = 1024 * 256;
        if (isbf) {
            const u16x8* s = (const u16x8*)pa.xsrc;
            u16x8* d = (u16x8*)pa.xdst;
            for (; i < pa.xn8; i += stride) d[i] = s[i];
        } else {
            const f32x4* s = (const f32x4*)pa.xsrc;
            for (; i < pa.xn8; i += stride) {
                f32x4 a = s[2 * i];
                f32x4 b = s[2 * i + 1];
                u16x8 o;
#pragma unroll
                for (int e = 0; e < 4; e++) {
                    o[e] = f2bf(a[e]);
                    o[4 + e] = f2bf(b[e]);
                }
                *(u16x8*)&pa.xdst[(size_t)i * 8] = o;
            }
        }
    }
}

#define F_SPLIT 1
#define F_BIAS  2
#define F_RELU  4

// ---------------------------------------------------------------------------
// gemm256 (r21 core + r23 XCD remap): 256x256 tile, 512 thr (8 waves 2Mx4N),
// BK=64, double-buffered, minimum-2-phase, XOR-swizzled staging,
// LDS-transpose epilogue. 1D grid; remap by=(id&7)*4 + q/nx co-locates all
// blocks sharing an A-panel on one XCD L2 (mechanism proven by r22 attn
// FETCH 69.8->16.5MB). Requires gridDim%8==0, (grid/8)%nx==0, M/256==32.
// ---------------------------------------------------------------------------
template <int FLAGS>
__global__ __launch_bounds__(512, 2) void gemm256(
    const u16* __restrict__ A, const u16* __restrict__ Bt,
    const u16* __restrict__ bias, u16* __restrict__ C,
    int M, int N, int K)
{
    // [buf0: A 16384 | B 16384][buf1: A | B][8 x 1536 epilogue slices]
    __shared__ __align__(16) u16 POOL[65536 + 8 * 1536];

    const int tid = threadIdx.x;          // 0..511
    const int lane = tid & 63;
    const int wave = tid >> 6;            // 0..7
    const int lrow = lane & 15;
    const int quad = lane >> 4;
    const int rswg = lrow & 7;
    const int wm = wave >> 2;             // 0..1
    const int wn = wave & 3;              // 0..3

    // XCD remap: p = id&7 owns A-panel rows by in [p*4, p*4+4).
    const int id = blockIdx.x;
    const int nx = N >> 8;
    const int p = id & 7;
    const int q = id >> 3;
    const int qd = q / nx;
    const int by = p * 4 + qd;
    const int bx = q - qd * nx;
    const int m0 = by * 256;
    const int n0 = bx * 256;

    const u16* Asrc[4];
    const u16* Bsrc[4];
#pragma unroll
    for (int r = 0; r < 4; r++) {
        const int idx = r * 512 + tid;
        const int row = idx >> 3;
        const int g = (idx & 7) ^ (row & 7);
        Asrc[r] = A + (size_t)(m0 + row) * K + g * 8;
        Bsrc[r] = Bt + (size_t)(n0 + row) * K + g * 8;
    }

#define STG256(BUF, K0)                                                      \
    {                                                                        \
        _Pragma("unroll")                                                    \
        for (int r = 0; r < 4; r++) {                                        \
            dma16(Asrc[r] + (K0), &POOL[(BUF) * 32768 + r * 4096 + wave * 512]); \
            dma16(Bsrc[r] + (K0), &POOL[(BUF) * 32768 + 16384 + r * 4096 + wave * 512]); \
        }                                                                    \
    }

    f32x4 acc[8][4];
#pragma unroll
    for (int mi = 0; mi < 8; mi++)
#pragma unroll
        for (int ni = 0; ni < 4; ni++) acc[mi][ni] = f32x4{0.f, 0.f, 0.f, 0.f};

    const int NT = K >> 6;
    STG256(0, 0)

    for (int j = 0; j < NT; j++) {
        asm volatile("s_waitcnt vmcnt(0)" ::: "memory");
        __builtin_amdgcn_sched_barrier(0);
        __builtin_amdgcn_s_barrier();
        __builtin_amdgcn_sched_barrier(0);
        if (j + 1 < NT) STG256((j + 1) & 1, (j + 1) * 64)

        const char* Ab = (const char*)&POOL[(j & 1) * 32768];
        const char* Bb = (const char*)&POOL[(j & 1) * 32768 + 16384];
#pragma unroll
        for (int ks = 0; ks < 2; ks++) {
            bf16x8 af[8], bfr[4];
#pragma unroll
            for (int mi = 0; mi < 8; mi++) {
                const int row = wm * 128 + mi * 16 + lrow;
                af[mi] = *(const bf16x8*)(Ab + row * 128 +
                                          (((ks * 4 + quad) ^ rswg) << 4));
            }
#pragma unroll
            for (int ni = 0; ni < 4; ni++) {
                const int row = wn * 64 + ni * 16 + lrow;
                bfr[ni] = *(const bf16x8*)(Bb + row * 128 +
                                           (((ks * 4 + quad) ^ rswg) << 4));
            }
#pragma unroll
            for (int mi = 0; mi < 8; mi++)
#pragma unroll
                for (int ni = 0; ni < 4; ni++)
                    acc[mi][ni] = __builtin_amdgcn_mfma_f32_16x16x32_bf16(
                        af[mi], bfr[ni], acc[mi][ni], 0, 0, 0);
        }
    }
#undef STG256

    // ---- epilogue: per-wave LDS-transpose store (3KB slice, wave-private).
    u16* st = POOL + 65536 + wave * 1536;
    const int mbase = m0 + wm * 128;
    const int nbase = n0 + wn * 64;
    const int msub = mbase & 4095;
    const int bb = mbase >> 12;
    const bool vpath = (FLAGS & F_SPLIT) && ((nbase >> 9) == 2);

    if (vpath) {
        const int h = (nbase >> 6) & 7;
        u16* vdst = C + 2 * NXC + (((size_t)(bb * CH + h)) * CDK) * CS;
#pragma unroll
        for (int mi = 0; mi < 8; mi++) {
#pragma unroll
            for (int ni = 0; ni < 4; ni++)
#pragma unroll
                for (int r = 0; r < 4; r++)
                    st[(ni * 16 + lrow) * 24 + quad * 4 + r] = f2bf(acc[mi][ni][r]);
#pragma unroll
            for (int rr = 0; rr < 2; rr++) {
                const int idx = rr * 64 + lane;
                const int dk = idx >> 1;
                const int sch = idx & 1;
                u16x8 val = *(const u16x8*)&st[dk * 24 + sch * 8];
                *(u16x8*)&vdst[(size_t)dk * CS + msub + mi * 16 + sch * 8] = val;
            }
        }
    } else {
        float bv[4];
        if (FLAGS & F_BIAS) {
#pragma unroll
            for (int ni = 0; ni < 4; ni++) bv[ni] = bf2f(bias[nbase + ni * 16 + lrow]);
        }
        const int proj = nbase >> 9;
        const int h = (nbase >> 6) & 7;
        u16* qkdst = C + (size_t)proj * NXC + (((size_t)(bb * CH + h)) * CS) * CDK;
#pragma unroll
        for (int mi = 0; mi < 8; mi++) {
#pragma unroll
            for (int ni = 0; ni < 4; ni++)
#pragma unroll
                for (int r = 0; r < 4; r++) {
                    float val = acc[mi][ni][r];
                    if (FLAGS & F_BIAS) val += bv[ni];
                    if (FLAGS & F_RELU) val = fmaxf(val, 0.f);
                    st[(quad * 4 + r) * 68 + ni * 16 + lrow] = f2bf(val);
                }
#pragma unroll
            for (int rr = 0; rr < 2; rr++) {
                const int idx = rr * 64 + lane;
                const int row = idx >> 3;
                const int ch = idx & 7;
                u16x4 lo = *(const u16x4*)&st[row * 68 + ch * 8];
                u16x4 hi = *(const u16x4*)&st[row * 68 + ch * 8 + 4];
                u16x8 val;
#pragma unroll
                for (int e = 0; e < 4; e++) { val[e] = lo[e]; val[4 + e] = hi[e]; }
                u16* pp;
                if (FLAGS & F_SPLIT)
                    pp = qkdst + (size_t)(msub + mi * 16 + row) * CDK + ch * 8;
                else
                    pp = C + (size_t)(mbase + mi * 16 + row) * N + nbase + ch * 8;
                *(u16x8*)pp = val;
            }
        }
    }
}

// ---------------------------------------------------------------------------
// MFMA GEMM 128^2 (WO/FF2). PIPE=1 reverted to r20 depth-3 (r22's depth-6
// regressed +4.4us): BK=32 rotating buffers, counted vmcnt(4)/(0),
// per-wave LDS-transpose epilogue.
// ---------------------------------------------------------------------------
template <int FLAGS, int PIPE>
__global__ __launch_bounds__(256, PIPE ? 1 : 3) void gemm_mfma(
    const u16* __restrict__ A, const u16* __restrict__ Bt,
    const u16* __restrict__ bias, u16* __restrict__ C,
    int M, int N, int K)
{
    constexpr int ABn = PIPE ? 12288 : 8192;   // u16 per matrix region
    __shared__ __align__(16) u16 POOL[2 * ABn + 4 * 1536];
    u16* ASb = POOL;
    u16* BSb = POOL + ABn;

    const int tid = threadIdx.x;
    const int lane = tid & 63;
    const int wave = tid >> 6;
    const int lrow = lane & 15;
    const int quad = lane >> 4;
    const int wm = wave & 1;
    const int wn = wave >> 1;
    const int m0 = blockIdx.y * 128;
    const int n0 = blockIdx.x * 128;

    f32x4 acc[4][4];
#pragma unroll
    for (int i = 0; i < 4; i++)
#pragma unroll
        for (int j = 0; j < 4; j++) acc[i][j] = f32x4{0.f, 0.f, 0.f, 0.f};

    if constexpr (PIPE) {
        // depth-3 counted-vmcnt pipeline, BK=32 (r20 verified config).
        const int idx0 = wave * 128 + lane;
        const int idx1 = idx0 + 64;
        const u16* Ap0 = A + (size_t)(m0 + (idx0 >> 2)) * K + (idx0 & 3) * 8;
        const u16* Ap1 = A + (size_t)(m0 + (idx1 >> 2)) * K + (idx1 & 3) * 8;
        const u16* Bp0 = Bt + (size_t)(n0 + (idx0 >> 2)) * K + (idx0 & 3) * 8;
        const u16* Bp1 = Bt + (size_t)(n0 + (idx1 >> 2)) * K + (idx1 & 3) * 8;
        const int NK = K >> 5;

#define PSTAGE(BOFF, KOFF)                                                   \
        {                                                                    \
            dma16(Ap0 + (KOFF), ASb + (BOFF) + wave * 1024);                 \
            dma16(Ap1 + (KOFF), ASb + (BOFF) + wave * 1024 + 512);           \
            dma16(Bp0 + (KOFF), BSb + (BOFF) + wave * 1024);                 \
            dma16(Bp1 + (KOFF), BSb + (BOFF) + wave * 1024 + 512);           \
        }
        PSTAGE(0, 0)
        PSTAGE(4096, 32)
        u32 bR = 0;
        for (int j = 0; j < NK; j++) {
            if (j < NK - 1) { asm volatile("s_waitcnt vmcnt(4)" ::: "memory"); }
            else            { asm volatile("s_waitcnt vmcnt(0)" ::: "memory"); }
            __builtin_amdgcn_sched_barrier(0);
            __builtin_amdgcn_s_barrier();
            __builtin_amdgcn_sched_barrier(0);
            if (j + 2 < NK) {
                u32 bS = bR + 8192;
                if (bS >= 12288) bS -= 12288;
                PSTAGE(bS, (j + 2) * 32)
            }
            bf16x8 af[4], bfr[4];
#pragma unroll
            for (int i = 0; i < 4; i++)
                af[i] = *(const bf16x8*)&ASb[bR + (wm * 64 + i * 16 + lrow) * 32 + quad * 8];
#pragma unroll
            for (int jj = 0; jj < 4; jj++)
                bfr[jj] = *(const bf16x8*)&BSb[bR + (wn * 64 + jj * 16 + lrow) * 32 + quad * 8];
#pragma unroll
            for (int i = 0; i < 4; i++)
#pragma unroll
                for (int jj = 0; jj < 4; jj++)
                    acc[i][jj] = __builtin_amdgcn_mfma_f32_16x16x32_bf16(
                        af[i], bfr[jj], acc[i][jj], 0, 0, 0);
            bR = (bR == 8192u) ? 0u : bR + 4096u;
        }
#undef PSTAGE
    } else {
        const int rswg = lrow & 7;
        const u16* Aps[4];
        const u16* Bps[4];
        u16* Adst[4];
        u16* Bdst[4];
#pragma unroll
        for (int r = 0; r < 4; r++) {
            const int idx = r * 256 + tid;
            const int row = idx >> 3;
            const int g = (idx & 7) ^ (row & 7);
            Aps[r] = A + (size_t)(m0 + row) * K + g * 8;
            Bps[r] = Bt + (size_t)(n0 + row) * K + g * 8;
            Adst[r] = &ASb[r * 2048 + wave * 512];
            Bdst[r] = &BSb[r * 2048 + wave * 512];
        }
        const char* As8 = (const char*)ASb;
        const char* Bs8 = (const char*)BSb;

        for (int k0 = 0; k0 < K; k0 += 64) {
            __syncthreads();
#pragma unroll
            for (int r = 0; r < 4; r++) {
                dma16(Aps[r] + k0, Adst[r]);
                dma16(Bps[r] + k0, Bdst[r]);
            }
            __syncthreads();

#pragma unroll
            for (int kk = 0; kk < 2; kk++) {
                bf16x8 af[4], bfr[4];
#pragma unroll
                for (int i = 0; i < 4; i++) {
                    const int row = wm * 64 + i * 16 + lrow;
                    af[i] = *(const bf16x8*)(As8 + row * 128 +
                                             (((kk * 4 + quad) ^ rswg) << 4));
                }
#pragma unroll
                for (int j = 0; j < 4; j++) {
                    const int row = wn * 64 + j * 16 + lrow;
                    bfr[j] = *(const bf16x8*)(Bs8 + row * 128 +
                                              (((kk * 4 + quad) ^ rswg) << 4));
                }
#pragma unroll
                for (int i = 0; i < 4; i++)
#pragma unroll
                    for (int j = 0; j < 4; j++)
                        acc[i][j] = __builtin_amdgcn_mfma_f32_16x16x32_bf16(
                            af[i], bfr[j], acc[i][j], 0, 0, 0);
            }
        }
    }

    // ---- epilogue: per-wave LDS-transpose store (3KB slice, no barriers).
    u16* st = POOL + 2 * ABn + wave * 1536;
    const int mbase = m0 + wm * 64;
    const int nbase = n0 + wn * 64;
    const int msub = mbase & 4095;
    const int bb = mbase >> 12;
    const bool vpath = (FLAGS & F_SPLIT) && ((nbase >> 9) == 2);

    if (vpath) {
        const int h = (nbase >> 6) & 7;
        u16* vdst = C + 2 * NXC + (((size_t)(bb * CH + h)) * CDK) * CS;
#pragma unroll
        for (int i = 0; i < 4; i++) {
#pragma unroll
            for (int j = 0; j < 4; j++)
#pragma unroll
                for (int r = 0; r < 4; r++)
                    st[(j * 16 + lrow) * 24 + quad * 4 + r] = f2bf(acc[i][j][r]);
#pragma unroll
            for (int rr = 0; rr < 2; rr++) {
                const int idx = rr * 64 + lane;
                const int dk = idx >> 1;
                const int sch = idx & 1;
                u16x8 val = *(const u16x8*)&st[dk * 24 + sch * 8];
                *(u16x8*)&vdst[(size_t)dk * CS + msub + i * 16 + sch * 8] = val;
            }
        }
    } else {
        float bv[4];
        if (FLAGS & F_BIAS) {
#pragma unroll
            for (int j = 0; j < 4; j++) bv[j] = bf2f(bias[nbase + j * 16 + lrow]);
        }
        const int proj = nbase >> 9;
        const int h = (nbase >> 6) & 7;
        u16* qkdst = C + (size_t)proj * NXC + (((size_t)(bb * CH + h)) * CS) * CDK;
#pragma unroll
        for (int i = 0; i < 4; i++) {
#pragma unroll
            for (int j = 0; j < 4; j++)
#pragma unroll
                for (int r = 0; r < 4; r++) {
                    float val = acc[i][j][r];
                    if (FLAGS & F_BIAS) val += bv[j];
                    if (FLAGS & F_RELU) val = fmaxf(val, 0.f);
                    st[(quad * 4 + r) * 68 + j * 16 + lrow] = f2bf(val);
                }
#pragma unroll
            for (int rr = 0; rr < 2; rr++) {
                const int idx = rr * 64 + lane;
                const int row = idx >> 3;
                const int ch = idx & 7;
                u16x4 lo = *(const u16x4*)&st[row * 68 + ch * 8];
                u16x4 hi = *(const u16x4*)&st[row * 68 + ch * 8 + 4];
                u16x8 val;
#pragma unroll
                for (int e = 0; e < 4; e++) { val[e] = lo[e]; val[4 + e] = hi[e]; }
                u16* pp;
                if (FLAGS & F_SPLIT)
                    pp = qkdst + (size_t)(msub + i * 16 + row) * CDK + ch * 8;
                else
                    pp = C + (size_t)(mbase + i * 16 + row) * N + nbase + ch * 8;
                *(u16x8*)pp = val;
            }
        }
    }
}

// ---------------------------------------------------------------------------
// Split-K transposed-score MFMA flash attention (r22, frozen: r15 structure
// + T5 setprio + XCD swizzle; 95.8us, FETCH 16.5MB). 1D grid of 1024;
// bijective remap id%8 = pair%8. Depth-3 K / depth-2 V counted-vmcnt (4/6).
// Epilogue stores transposed pOT[z][bh][dk][s].
// ---------------------------------------------------------------------------
__global__ __launch_bounds__(256, 4) void mfma_attn2(
    const u16* __restrict__ Qb, const u16* __restrict__ Kb,
    const u16* __restrict__ Vt, const unsigned long long* __restrict__ bits,
    u16* __restrict__ pOT, float* __restrict__ Ls)
{
    __shared__ u16 KB[3][4096];   // K tiles, rotating depth-3
    __shared__ u16 VB[2][4096];   // V tiles, parity depth-2

    const int tid = threadIdx.x;
    const int lane = tid & 63;
    const int wave = tid >> 6;
    const int qcol = lane & 31;
    const int hf = lane >> 5;

    // XCD swizzle: id -> (pair p = bh*2+z, qtile qx) with id%8 == p%8.
    const int id = blockIdx.x;
    const int xcd = id & 7;
    const int jL = id >> 3;
    const int p = ((jL >> 5) << 3) | xcd;
    const int qx = jL & 31;
    const int bh = p >> 1;
    const int z = p & 1;
    const int b = bh >> 3;
    const int q0 = qx * 128 + wave * 32;

    const float SC = 0.125f * 1.44269504088896340736f;  // 1/sqrt(64)*log2(e)

    bf16x8 bq[4];
    const u16* qp = Qb + ((size_t)bh * CS + q0 + qcol) * CDK + hf * 8;
#pragma unroll
    for (int c = 0; c < 4; c++) {
        bf16x8 raw = *(const bf16x8*)(qp + c * 16);
        union { u32 u[4]; bf16x8 v; } cv;
#pragma unroll
        for (int j = 0; j < 4; j++)
            cv.u[j] = packbf2(bf2f((u16)raw[2 * j]) * SC, bf2f((u16)raw[2 * j + 1]) * SC);
        bq[c] = cv.v;
    }

    // Opaque zero accumulator (16 VGPRs, no remat) for first QK^T MFMA.
    f32x4 z4 = {0.f, 0.f, 0.f, 0.f};
    asm volatile("" : "+v"(z4));
    f32x16 zero16;
#pragma unroll
    for (int i = 0; i < 16; i++) zero16[i] = z4[i & 3];

    f32x16 ot[2];
#pragma unroll
    for (int dt = 0; dt < 2; dt++)
#pragma unroll
        for (int i = 0; i < 16; i++) ot[dt][i] = 0.f;
    float lh = 0.f;   // per-half row-sum; cross-half reduce in epilogue

    const u16* kbase = Kb + (size_t)bh * CS * CDK;
    const u16* vbase = Vt + (size_t)bh * CDK * CS;
    const unsigned long long* bp = bits + b * 64;

    const int t0 = z * (CS / NSP);
    const int t1 = t0 + (CS / NSP);

    // Loop-invariant per-lane LDS byte offsets for the swizzled K/V reads.
    const int rsw = qcol & 7;
    int koff[2][4];
#pragma unroll
    for (int rt = 0; rt < 2; rt++)
#pragma unroll
        for (int c = 0; c < 4; c++)
            koff[rt][c] = ((rt * 32 + qcol) * 64 + (((2 * c + hf) ^ rsw) * 8)) * 2;
    const char* kb0 = (const char*)&KB[0][0];
    const char* vb0 = (const char*)&VB[0][0];

    const int w2 = wave * 2;

#define STAGE_K(KOFFB, t)                                                    \
    {                                                                        \
        const u16* kb_ = kbase + (size_t)(t) * CDK;                          \
        _Pragma("unroll")                                                    \
        for (int n = 0; n < 2; n++) {                                        \
            int idx = (w2 + n) * 64 + lane;                                  \
            int row = idx >> 3;                                              \
            int g = (idx & 7) ^ (row & 7);                                   \
            dma16(kb_ + row * CDK + g * 8,                                   \
                  (u16*)((char*)&KB[0][0] + (KOFFB) + (w2 + n) * 1024));     \
        }                                                                    \
    }
#define STAGE_V(P, t)                                                        \
    {                                                                        \
        const u16* vb_ = vbase + (t);                                        \
        _Pragma("unroll")                                                    \
        for (int n = 0; n < 2; n++) {                                        \
            int idx = (w2 + n) * 64 + lane;                                  \
            int row = idx >> 3;                                              \
            int g = (idx & 7) ^ (row & 7);                                   \
            dma16(vb_ + (size_t)row * CS + g * 8,                            \
                  (u16*)((char*)&VB[0][0] + (P) * 8192 + (w2 + n) * 1024));  \
        }                                                                    \
    }

// Tile compute body. MIDSYNC inserted after the mt=0 softmax (before any
// V read). MASKED is a compile-time flag; BM only evaluated when MASKED.
// T5: setprio(1) around the QK^T and PV MFMA clusters (m191: +4-7% attn).
#define TBODY(KROFF, VOFF, BM, MASKED, MIDSYNC)                              \
    {                                                                        \
        f32x2 racc = {0.f, 0.f};                                             \
        _Pragma("unroll")                                                    \
        for (int mt = 0; mt < 2; mt++) {                                     \
            f32x16 s;                                                        \
            __builtin_amdgcn_s_setprio(1);                                   \
            _Pragma("unroll")                                                \
            for (int c = 0; c < 4; c++) {                                    \
                bf16x8 ak = *(const bf16x8*)(kb0 + (KROFF) + koff[mt][c]);   \
                s = __builtin_amdgcn_mfma_f32_32x32x16_bf16(                 \
                    ak, bq[c], (c == 0) ? zero16 : s, 0, 0, 0);              \
            }                                                                \
            __builtin_amdgcn_s_setprio(0);                                   \
            if (MASKED) {                                                    \
                const unsigned long long bm_ = (BM);                         \
                if (bm_ != ~0ull) {                                          \
                    _Pragma("unroll")                                        \
                    for (int i = 0; i < 16; i++) {                           \
                        const int key = (i & 3) + 8 * (i >> 2) + 4 * hf + 32 * mt; \
                        if (!((bm_ >> key) & 1ull)) s[i] = -1e30f;           \
                    }                                                        \
                }                                                            \
            }                                                                \
            u32 pk[8];                                                       \
            _Pragma("unroll")                                                \
            for (int g = 0; g < 4; g++) {                                    \
                float p0 = __builtin_amdgcn_exp2f(s[4 * g + 0]);             \
                float p1 = __builtin_amdgcn_exp2f(s[4 * g + 1]);             \
                float p2 = __builtin_amdgcn_exp2f(s[4 * g + 2]);             \
                float p3 = __builtin_amdgcn_exp2f(s[4 * g + 3]);             \
                racc += f32x2{p0, p1};                                       \
                racc += f32x2{p2, p3};                                       \
                pk[2 * g + 0] = packbf2(p0, p1);                             \
                pk[2 * g + 1] = packbf2(p2, p3);                             \
            }                                                                \
            if (mt == 0) { MIDSYNC }                                         \
            _Pragma("unroll")                                                \
            for (int cc = 0; cc < 2; cc++) {                                 \
                u32x2 r0 = __builtin_amdgcn_permlane32_swap(                 \
                    pk[4 * cc + 0], pk[4 * cc + 2], false, false);           \
                u32x2 r1 = __builtin_amdgcn_permlane32_swap(                 \
                    pk[4 * cc + 1], pk[4 * cc + 3], false, false);           \
                union { u32 u[4]; bf16x8 v; } pf;                            \
                pf.u[0] = r0.x;                                              \
                pf.u[1] = r1.x;                                              \
                pf.u[2] = r0.y;                                              \
                pf.u[3] = r1.y;                                              \
                const int c = 2 * mt + cc;                                   \
                __builtin_amdgcn_s_setprio(1);                               \
                _Pragma("unroll")                                            \
                for (int dt = 0; dt < 2; dt++) {                             \
                    bf16x8 av = *(const bf16x8*)(vb0 + (VOFF) + koff[dt][c]); \
                    ot[dt] = __builtin_amdgcn_mfma_f32_32x32x16_bf16(        \
                        av, pf.v, ot[dt], 0, 0, 0);                          \
                }                                                            \
                __builtin_amdgcn_s_setprio(0);                               \
            }                                                                \
        }                                                                    \
        lh += racc.x + racc.y;                                               \
    }

// Pipelined fast-path tile. TOPASM ensures K(j) done, MIDASM ensures V(j)
// done; barriers make it cross-wave. Stages issued after the top barrier:
// V(j+1) first, then K(j+2) (issue order defines vmcnt retirement order).
#define FTILE(P, TT, KR, KS, DOV, DOK, TOPASM, MIDASM)                       \
    {                                                                        \
        asm volatile(TOPASM ::: "memory");                                   \
        __builtin_amdgcn_sched_barrier(0);                                   \
        __builtin_amdgcn_s_barrier();                                        \
        __builtin_amdgcn_sched_barrier(0);                                   \
        if (DOV) STAGE_V((P) ^ 1, (TT) + 64);                                \
        if (DOK) STAGE_K((KS), (TT) + 128);                                  \
        TBODY((KR), (P) * 8192, 0ull, 0,                                     \
              asm volatile(MIDASM ::: "memory");                             \
              __builtin_amdgcn_sched_barrier(0);                             \
              __builtin_amdgcn_s_barrier();                                  \
              __builtin_amdgcn_sched_barrier(0);)                            \
    }

    // ---- mask precheck (hoisted; no vector loads inside the counted loop)
    unsigned long long am = ~0ull;
    const int tb0 = t0 >> 6;
    for (int i = 0; i < 32; i++) am &= bp[tb0 + i];
    const bool allones = (am == ~0ull);

    if (allones) {
        // prologue: K(0), V(0), K(1)  (oldest-first order matters for vmcnt)
        STAGE_K(0, t0);
        STAGE_V(0, t0);
        STAGE_K(8192, t0 + 64);

        u32 kr = 0;
        for (int m = 0; m < 15; m++) {
            const int t = t0 + m * 128;
            const u32 kr1 = (kr == 16384u) ? 0u : kr + 8192u;
            const u32 ks0 = (kr1 == 16384u) ? 0u : kr1 + 8192u;
            FTILE(0, t, kr, ks0, 1, 1,
                  "s_waitcnt vmcnt(4)", "s_waitcnt vmcnt(6)")
            FTILE(1, t + 64, kr1, kr, 1, 1,
                  "s_waitcnt vmcnt(4)", "s_waitcnt vmcnt(6)")
            kr = ks0;
        }
        {   // tiles 30, 31 (peeled: adjusted counts, no K stages)
            const int t = t0 + 30 * 64;
            const u32 kr1 = (kr == 16384u) ? 0u : kr + 8192u;
            FTILE(0, t, kr, 0, 1, 0,
                  "s_waitcnt vmcnt(4)", "s_waitcnt vmcnt(4)")
            FTILE(1, t + 64, kr1, 0, 0, 0,
                  "s_waitcnt vmcnt(2)", "s_waitcnt vmcnt(0)")
        }
    } else {
        // slow path: depth-1 double buffer with __syncthreads.
        STAGE_K(0, t0);
        STAGE_V(0, t0);
        __syncthreads();
        for (int t = t0; t < t1; t += 64) {
            const int pp = (t >> 6) & 1;
            const u32 kro = (u32)pp * 8192u;
            if (t + 64 < t1) {
                STAGE_V(pp ^ 1, t + 64);
                STAGE_K((pp ^ 1) * 8192, t + 64);
            }
            TBODY(kro, pp * 8192, bp[t >> 6], 1, ;)
            __syncthreads();
        }
    }
#undef FTILE
#undef TBODY
#undef STAGE_V
#undef STAGE_K

    // ---- epilogue: cross-half l reduce, unnormalized partial O^T + l
    u32x2 rr = __builtin_amdgcn_permlane32_swap(
        __float_as_uint(lh), __float_as_uint(lh), false, false);
    const float l = lh + __uint_as_float(hf ? rr.x : rr.y);

    const int q_lin = bh * CS + q0 + qcol;
    if (hf == 0) Ls[z * BHS + q_lin] = l;
    const size_t pbase = ((size_t)(z * BH + bh) * CDK) * CS + q0 + qcol;
#pragma unroll
    for (int dt = 0; dt < 2; dt++)
#pragma unroll
        for (int i = 0; i < 16; i++) {
            const int dk = (i & 3) + 8 * (i >> 2) + 4 * hf + 32 * dt;
            pOT[pbase + (size_t)dk * CS] = f2bf(ot[dt][i]);
        }
}

// ---------------------------------------------------------------------------
// Combine NSP partials -> ctx [B,S,D]. Reads pOT coalesced along s, LDS
// transpose, writes ctx coalesced along d. grid (CS/64, BH).
// ---------------------------------------------------------------------------
__global__ __launch_bounds__(256) void attn_combine(
    const u16* __restrict__ pOT, const float* __restrict__ Ls,
    u16* __restrict__ ctx)
{
    __shared__ float linv[64];
    __shared__ u16 T[64][72];   // [s][dk], padded

    const int bh = blockIdx.y;
    const int s0 = blockIdx.x * 64;
    const int b = bh >> 3, h = bh & 7;
    const int tid = threadIdx.x;

    if (tid < 64) {
        float L = 0.f;
#pragma unroll
        for (int z = 0; z < NSP; z++) L += Ls[z * BHS + bh * CS + s0 + tid];
        linv[tid] = (L > 0.f) ? 1.f / L : 0.f;
    }
    __syncthreads();

    const int dk = tid >> 2;
    const int sc = (tid & 3) * 16;
    float acc[16] = {};
#pragma unroll
    for (int z = 0; z < NSP; z++) {
        const u16* p = pOT + ((size_t)(z * BH + bh) * CDK + dk) * CS + s0 + sc;
        u16x8 v0 = *(const u16x8*)p;
        u16x8 v1 = *(const u16x8*)(p + 8);
#pragma unroll
        for (int e = 0; e < 8; e++) {
            acc[e] += bf2f(v0[e]);
            acc[8 + e] += bf2f(v1[e]);
        }
    }
#pragma unroll
    for (int e = 0; e < 16; e++)
        T[sc + e][dk] = f2bf(acc[e] * linv[sc + e]);
    __syncthreads();

    const int sr = tid >> 2;
    const int dc = (tid & 3) * 16;
    u16x8 o0, o1;
#pragma unroll
    for (int e = 0; e < 8; e++) {
        o0[e] = T[sr][dc + e];
        o1[e] = T[sr][dc + 8 + e];
    }
    u16* cp = &ctx[((size_t)b * CS + s0 + sr) * CD + h * CDK + dc];
    *(u16x8*)cp = o0;
    *(u16x8*)(cp + 8) = o1;
}

// ---------------------------------------------------------------------------
// Residual + LayerNorm (unchanged).
// ---------------------------------------------------------------------------
__global__ __launch_bounds__(256) void ln_kernel(
    const u16* __restrict__ xa, const u16* __restrict__ xb,
    const u16* __restrict__ g, const u16* __restrict__ be,
    u16* __restrict__ outb, float* __restrict__ outf,
    const int* __restrict__ flag)
{
    const int lane = threadIdx.x & 63;
    const int wave = threadIdx.x >> 6;
    const size_t row = (size_t)blockIdx.x * 4 + wave;
    const int c0 = lane * 8;

    u16x8 av = *(const u16x8*)(xa + row * CD + c0);
    u16x8 bv = *(const u16x8*)(xb + row * CD + c0);

    float v[8];
    float s1 = 0.f, s2 = 0.f;
#pragma unroll
    for (int e = 0; e < 8; e++) {
        v[e] = bf2f(av[e]) + bf2f(bv[e]);
        s1 += v[e];
        s2 += v[e] * v[e];
    }
#pragma unroll
    for (int off = 32; off > 0; off >>= 1) {
        s1 += __shfl_xor(s1, off, 64);
        s2 += __shfl_xor(s2, off, 64);
    }
    const float mu = s1 * (1.f / CD);
    const float var = fmaxf(s2 * (1.f / CD) - mu * mu, 0.f);
    const float r = rsqrtf(var + 1e-5f);

    u16x8 gv = *(const u16x8*)(g + c0);
    u16x8 ev = *(const u16x8*)(be + c0);
    float res[8];
#pragma unroll
    for (int e = 0; e < 8; e++)
        res[e] = (v[e] - mu) * r * bf2f(gv[e]) + bf2f(ev[e]);

    const int flg = *flag;
    const bool f32out = (outf != nullptr) && (flg == 0);
    if (f32out) {
        float4 o0 = make_float4(res[0], res[1], res[2], res[3]);
        float4 o1 = make_float4(res[4], res[5], res[6], res[7]);
        *(float4*)(outf + row * CD + c0) = o0;
        *(float4*)(outf + row * CD + c0 + 4) = o1;
    } else {
        u16x8 ov;
#pragma unroll
        for (int e = 0; e < 8; e++) ov[e] = f2bf(res[e]);
        *(u16x8*)(outb + row * CD + c0) = ov;
    }
}

// ---------------------------------------------------------------------------

extern "C" void kernel_launch(void* const* d_in, const int* in_sizes, int n_in,
                              void* d_out, int out_size, void* d_ws, size_t ws_size,
                              hipStream_t stream)
{
    const void* x_raw   = d_in[0];
    const int*  mask    = (const int*)d_in[1];
    const void* wq_raw  = d_in[2];
    const void* wk_raw  = d_in[3];
    const void* wv_raw  = d_in[4];
    const void* wo_raw  = d_in[5];
    const void* w1_raw  = d_in[6];
    const void* b1_raw  = d_in[7];
    const void* w2_raw  = d_in[8];
    const void* b2_raw  = d_in[9];
    const void* g1_raw  = d_in[10];
    const void* be1_raw = d_in[11];
    const void* g2_raw  = d_in[12];
    const void* be2_raw = d_in[13];

    const size_t NX = NXC;
    const size_t WSZ = (size_t)CD * CD;
    const size_t W1SZ = (size_t)CD * CDFF;

    u16* ws = (u16*)d_ws;
    int* flag = (int*)d_ws;
    unsigned long long* bits = (unsigned long long*)(ws + 512);
    u16* base = ws + 1024;
    u16* xc  = base;
    u16* q   = base + 1 * NX;
    u16* k   = base + 2 * NX;
    u16* v   = base + 3 * NX;   // V^T [B,H,DK,S]
    u16* ctx = base + 4 * NX;
    u16* att = base + 5 * NX;   // also holds attn stats (Ls) pre-wo-gemm
    u16* x1  = base + 6 * NX;
    u16* ffo = base + 7 * NX;
    u16* ffh = base + 8 * NX;   // 4*NX; also holds attn partial O pre-FFN
    u16* wt  = base + 12 * NX;
    u16* wqkvT = wt;
    u16* woT = wqkvT + 3 * WSZ;
    u16* w1T = woT + WSZ;
    u16* w2T = w1T + W1SZ;
    u16* b1c = w2T + W1SZ;
    u16* b2c = b1c + CDFF;
    u16* g1c = b2c + CD;
    u16* be1c = g1c + CD;
    u16* g2c = be1c + CD;
    u16* be2c = g2c + CD;
    u16* wend = be2c + CD;

    const size_t need = (size_t)(wend - ws) * sizeof(u16);
    if (ws_size < need) return;
    (void)k;

    u16* pOT = ffh;                      // NSP*NX u16, [z][bh][dk][s]
    float* Ls = (float*)att;             // NSP*BHS floats

    // ---- fused preprocessing: detect + x-convert + 6 transposes + mask
    // bits + small converts, ONE dispatch (r23).
    PrepArgs pa;
    pa.tsrc[0] = wq_raw; pa.tdst[0] = wqkvT;           pa.R[0] = CD;   pa.Cc[0] = CD;
    pa.tsrc[1] = wk_raw; pa.tdst[1] = wqkvT + WSZ;     pa.R[1] = CD;   pa.Cc[1] = CD;
    pa.tsrc[2] = wv_raw; pa.tdst[2] = wqkvT + 2 * WSZ; pa.R[2] = CD;   pa.Cc[2] = CD;
    pa.tsrc[3] = wo_raw; pa.tdst[3] = woT;             pa.R[3] = CD;   pa.Cc[3] = CD;
    pa.tsrc[4] = w1_raw; pa.tdst[4] = w1T;             pa.R[4] = CD;   pa.Cc[4] = CDFF;
    pa.tsrc[5] = w2_raw; pa.tdst[5] = w2T;             pa.R[5] = CDFF; pa.Cc[5] = CD;
    int cum = 0;
    for (int w = 0; w < 6; w++) {
        pa.nbx[w] = pa.Cc[w] / 32;
        pa.cum[w] = cum;
        cum += (pa.Cc[w] / 32) * (pa.R[w] / 32);
    }
    pa.cum[6] = cum;                      // 3072
    pa.mask = mask;
    pa.bits = bits;
    pa.ssrc[0] = b1_raw;  pa.sdst[0] = b1c;  pa.sn[0] = CDFF;
    pa.ssrc[1] = b2_raw;  pa.sdst[1] = b2c;  pa.sn[1] = CD;
    pa.ssrc[2] = g1_raw;  pa.sdst[2] = g1c;  pa.sn[2] = CD;
    pa.ssrc[3] = be1_raw; pa.sdst[3] = be1c; pa.sn[3] = CD;
    pa.ssrc[4] = g2_raw;  pa.sdst[4] = g2c;  pa.sn[4] = CD;
    pa.ssrc[5] = be2_raw; pa.sdst[5] = be2c; pa.sn[5] = CD;
    pa.xw = (const u32*)x_raw;
    pa.xsrc = x_raw;
    pa.xdst = xc;
    pa.xn8 = (int)(NX >> 3);
    prep_all<<<cum + 32 + 1 + 1024, 256, 0, stream>>>(pa, flag);

    const int M = CB * CS;  // 8192

    // QKV + FF1 on the 256^2 8-wave kernel (1D grid, XCD-remapped);
    // WO + FF2 on the 128^2 PIPE=1 depth-3.
    gemm256<F_SPLIT><<<dim3((1536 / 256) * (M / 256)), 512, 0, stream>>>(
        xc, wqkvT, nullptr, q, M, 1536, CD);

    mfma_attn2<<<dim3(1024), 256, 0, stream>>>(q, k, v, bits, pOT, Ls);
    attn_combine<<<dim3(CS / 64, BH), 256, 0, stream>>>(pOT, Ls, ctx);

    gemm_mfma<0, 1><<<dim3(CD / 128, M / 128), 256, 0, stream>>>(
        ctx, woT, nullptr, att, M, CD, CD);

    ln_kernel<<<dim3(M / 4), 256, 0, stream>>>(xc, att, g1c, be1c, x1, nullptr, flag);

    gemm256<F_BIAS | F_RELU><<<dim3((CDFF / 256) * (M / 256)), 512, 0, stream>>>(
        x1, w1T, b1c, ffh, M, CDFF, CD);
    gemm_mfma<F_BIAS, 1><<<dim3(CD / 128, M / 128), 256, 0, stream>>>(
        ffh, w2T, b2c, ffo, M, CD, CDFF);

    ln_kernel<<<dim3(M / 4), 256, 0, stream>>>(x1, ffo, g2c, be2c,
                                               (u16*)d_out, (float*)d_out, flag);
}